// Round 1
// baseline (693.905 us; speedup 1.0000x reference)
//
#include <hip/hip_runtime.h>

// IsoMaxPlusLossFirstPart: logits[b,k,h,w] = -|scale| * || xn(b,:,h,w) - pn(k,:) ||
// via the reference's quadratic expansion d2 = xx + pp - 2*dot, with
// normalization folded into the epilogue: xn.pn = (x.pn)/max(||x||,eps).
//
// Memory-bound: 512 MiB feature read + 38 MiB write -> ~92 us floor @ 6.3 TB/s.
// Strategy: one thread = 4 consecutive w-pixels (float4 loads, coalesced along w
// for each channel c); 19 dot-accumulators + 1 norm-accumulator per pixel in
// VGPRs; prototypes L2-normalized per-block into LDS transposed [c][20] so each
// c-step reads all k via 5x ds_read_b128 broadcast (conflict-free).

namespace {
constexpr int kC   = 256;
constexpr int kK   = 19;
constexpr int kKP  = 20;            // padded K for b128 LDS reads (16B-aligned rows: 80 B)
constexpr int kHW  = 128 * 256;     // H*W = 32768
constexpr int kBlock = 256;
constexpr int kPixPerThread = 4;
}

__global__ __launch_bounds__(kBlock, 2)
void isomax_dist_kernel(const float* __restrict__ feat,
                        const float* __restrict__ proto,
                        const float* __restrict__ dscale,
                        float* __restrict__ out)
{
    __shared__ float pn_s[kC * kKP];   // [c][k] normalized prototypes (20.5 KiB)
    __shared__ float pp_s[kK];         // sum(pn^2) per k (post-normalization)

    const int tid  = threadIdx.x;
    const int lane = tid & 63;
    const int wv   = tid >> 6;         // wave id 0..3

    // ---- Phase 1: per-block prototype normalization into LDS ----
    // wave wv handles k = wv, wv+4, ... ; each lane covers 4 channels.
    for (int k = wv; k < kK; k += 4) {
        float v[4];
        float ss = 0.f;
        #pragma unroll
        for (int j = 0; j < 4; ++j) {
            v[j] = proto[k * kC + j * 64 + lane];   // coalesced across lanes
            ss = fmaf(v[j], v[j], ss);
        }
        #pragma unroll
        for (int m = 1; m < 64; m <<= 1)            // butterfly: all lanes get sum
            ss += __shfl_xor(ss, m, 64);
        const float nrm = sqrtf(ss);
        const float inv = 1.0f / fmaxf(nrm, 1e-12f);
        #pragma unroll
        for (int j = 0; j < 4; ++j)
            pn_s[(j * 64 + lane) * kKP + k] = v[j] * inv;
        if (lane == 0) pp_s[k] = ss * inv * inv;    // == sum(pn_normalized^2)
    }
    __syncthreads();

    // ---- Phase 2: single pass over channels ----
    const int gpix = (blockIdx.x * kBlock + tid) * kPixPerThread;  // flat pixel idx
    const int b    = gpix >> 15;          // / kHW
    const int hw   = gpix & (kHW - 1);    // % kHW
    const float* fp = feat + (size_t)b * kC * kHW + hw;

    float xx[4] = {0.f, 0.f, 0.f, 0.f};  // raw sum(x^2), one per pixel
    float4 dot[kK];                       // raw x.p, 4 pixels each
    #pragma unroll
    for (int k = 0; k < kK; ++k) dot[k] = make_float4(0.f, 0.f, 0.f, 0.f);

    for (int cc = 0; cc < kC; cc += 4) {
        float4 v[4];
        #pragma unroll
        for (int u = 0; u < 4; ++u)       // 4 independent 16B loads in flight
            v[u] = *(const float4*)(fp + (size_t)(cc + u) * kHW);
        #pragma unroll
        for (int u = 0; u < 4; ++u) {
            const int c = cc + u;
            float4 P[5];
            const float4* row = (const float4*)(pn_s + c * kKP);
            #pragma unroll
            for (int q = 0; q < 5; ++q) P[q] = row[q];   // 5x ds_read_b128 broadcast
            const float* p = (const float*)P;
            xx[0] = fmaf(v[u].x, v[u].x, xx[0]);
            xx[1] = fmaf(v[u].y, v[u].y, xx[1]);
            xx[2] = fmaf(v[u].z, v[u].z, xx[2]);
            xx[3] = fmaf(v[u].w, v[u].w, xx[3]);
            #pragma unroll
            for (int k = 0; k < kK; ++k) {
                dot[k].x = fmaf(p[k], v[u].x, dot[k].x);
                dot[k].y = fmaf(p[k], v[u].y, dot[k].y);
                dot[k].z = fmaf(p[k], v[u].z, dot[k].z);
                dot[k].w = fmaf(p[k], v[u].w, dot[k].w);
            }
        }
    }

    // ---- Epilogue: fold normalization, distance, scale ----
    float inv[4], xnsq[4];
    #pragma unroll
    for (int j = 0; j < 4; ++j) {
        const float nrm = sqrtf(xx[j]);
        inv[j]  = 1.0f / fmaxf(nrm, 1e-12f);
        xnsq[j] = xx[j] * inv[j] * inv[j];   // sum(xn^2), matches ref exactly in structure
    }
    const float sc = fabsf(dscale[0]);

    float* op = out + (size_t)b * kK * kHW + hw;
    #pragma unroll
    for (int k = 0; k < kK; ++k) {
        const float ppk = pp_s[k];
        float4 o;
        o.x = -sc * sqrtf(fmaxf(xnsq[0] + ppk - 2.0f * dot[k].x * inv[0], 0.f));
        o.y = -sc * sqrtf(fmaxf(xnsq[1] + ppk - 2.0f * dot[k].y * inv[1], 0.f));
        o.z = -sc * sqrtf(fmaxf(xnsq[2] + ppk - 2.0f * dot[k].z * inv[2], 0.f));
        o.w = -sc * sqrtf(fmaxf(xnsq[3] + ppk - 2.0f * dot[k].w * inv[3], 0.f));
        *(float4*)(op + (size_t)k * kHW) = o;   // coalesced along w per k
    }
}

extern "C" void kernel_launch(void* const* d_in, const int* in_sizes, int n_in,
                              void* d_out, int out_size, void* d_ws, size_t ws_size,
                              hipStream_t stream) {
    const float* feat   = (const float*)d_in[0];
    const float* proto  = (const float*)d_in[1];
    const float* dscale = (const float*)d_in[2];
    float* out = (float*)d_out;

    const int npix    = in_sizes[0] / kC;              // B*H*W = 524288
    const int threads = npix / kPixPerThread;          // 131072
    const dim3 grid(threads / kBlock);                 // 512 blocks
    isomax_dist_kernel<<<grid, kBlock, 0, stream>>>(feat, proto, dscale, out);
}